// Round 10
// baseline (24.380 us; speedup 1.0000x reference)
//
#include <hip/hip_runtime.h>
#include <hip/hip_bf16.h>

#define NBATCH 512
#define NS 66
#define ND 304
#define NK 128
#define NTHREADS 256       // 4 waves, each owns 32 t-cols
#define NCHUNK 10          // k-chunks of 32 (304 -> 320 padded)

#define CSTRIDE_B 64       // 32 bf16 per row per chunk buffer (one chunk)
#define CBYTES (80 * CSTRIDE_B)             // 5120 per buffer
#define TSTRIDE_B 256      // 128 bf16 per row
#define TBYTES (80 * TSTRIDE_B)             // 20480
#define NE 528             // 66 rows * 8 float4 staged per chunk

typedef __attribute__((ext_vector_type(8))) short bf16x8;
typedef __attribute__((ext_vector_type(4))) short s16x4;
typedef __attribute__((ext_vector_type(4))) float f32x4;

__device__ __forceinline__ short f2bf(float x) {
    return __builtin_bit_cast(short, __float2bfloat16(x));
}

// 15 upper-triangle 16x16 tiles of G: 5 diagonal first, then 10 strict-upper.
__device__ const int TI_LUT[15] = {0,1,2,3,4, 0,0,0,0,1,1,1,2,2,3};
__device__ const int TJ_LUT[15] = {0,1,2,3,4, 1,2,3,4,2,3,4,3,4,4};

// raw barrier: waits this wave's LDS ops + all waves arrive; vmem stays in flight
#define LDS_BARRIER() asm volatile("s_waitcnt lgkmcnt(0)\n\ts_barrier" ::: "memory")

__global__ __launch_bounds__(NTHREADS, 2) void treeprobe_mfma(
    const float* __restrict__ x,   // [512][66][304]
    const float* __restrict__ W,   // [128][304]
    float* __restrict__ out)       // [512][66][66]
{
    // LDS: 2 x-chunk buffers (swizzled) | t (swizzled) | norms
    __shared__ __align__(16) char xlds[2 * CBYTES];
    __shared__ __align__(16) char t_lds[TBYTES];
    __shared__ float norms[80];

    const int tid   = threadIdx.x;
    const int batch = blockIdx.x;
    const int lane  = tid & 63;
    const int wv    = tid >> 6;     // wave 0..3 : 32 t-cols each
    const int lr    = lane & 15;
    const int lg    = lane >> 4;    // 0..3

    const float* __restrict__ xb = x + (size_t)batch * NS * ND;

    // -------- staging helpers (macros keep everything statically indexed) ----
    // x chunk c: element e in [0,528): row=e>>3, kcol = c*32 + (e&7)*4
#define ISSUE_X(xr, c)                                                        \
    _Pragma("unroll")                                                         \
    for (int i = 0; i < 3; ++i) {                                             \
        const int e = tid + i * NTHREADS;                                     \
        float4 v = make_float4(0.f, 0.f, 0.f, 0.f);                           \
        if (e < NE) {                                                         \
            const int kc = (c) * 32 + (e & 7) * 4;                            \
            if (kc < ND)                                                      \
                v = *reinterpret_cast<const float4*>(xb + (e >> 3) * ND + kc);\
        }                                                                     \
        xr[i] = v;                                                            \
    }

    // W chunk c: per lane, rows (wv*2+nt)*16+lr, k = c*32 + lg*8 .. +7
#define ISSUE_W(wr4, c)                                                       \
    _Pragma("unroll")                                                         \
    for (int nt = 0; nt < 2; ++nt) {                                          \
        const int row = (wv * 2 + nt) * 16 + lr;                              \
        const int k0 = (c) * 32 + lg * 8;                                     \
        if (k0 < ND) {                                                        \
            wr4[nt * 2]     = *reinterpret_cast<const float4*>(W + row * ND + k0);     \
            wr4[nt * 2 + 1] = *reinterpret_cast<const float4*>(W + row * ND + k0 + 4); \
        } else {                                                              \
            wr4[nt * 2]     = make_float4(0.f, 0.f, 0.f, 0.f);                \
            wr4[nt * 2 + 1] = make_float4(0.f, 0.f, 0.f, 0.f);                \
        }                                                                     \
    }

    // convert+write x regs (8B quads). k-group m=(e&7)>>1 -> phys slot m^(row&3):
    // byte = row*64 + ((m ^ (row&3))<<4) + (e&1)*8
#define WRITE_X(xr, buf)                                                      \
    _Pragma("unroll")                                                         \
    for (int i = 0; i < 3; ++i) {                                             \
        const int e = tid + i * NTHREADS;                                     \
        if (e < NE) {                                                         \
            const int row = e >> 3;                                           \
            const int byte = row * CSTRIDE_B                                  \
                + (((((e & 7) >> 1) ^ (row & 3)) << 4) | ((e & 1) << 3));     \
            s16x4 sv;                                                         \
            sv[0] = f2bf(xr[i].x); sv[1] = f2bf(xr[i].y);                     \
            sv[2] = f2bf(xr[i].z); sv[3] = f2bf(xr[i].w);                     \
            *reinterpret_cast<s16x4*>(xlds + (buf) * CBYTES + byte) = sv;     \
        }                                                                     \
    }

#define CVT_W(wfrag, wr4)                                                     \
    _Pragma("unroll")                                                         \
    for (int nt = 0; nt < 2; ++nt) {                                          \
        bf16x8 f;                                                             \
        f[0] = f2bf(wr4[nt * 2].x);     f[1] = f2bf(wr4[nt * 2].y);           \
        f[2] = f2bf(wr4[nt * 2].z);     f[3] = f2bf(wr4[nt * 2].w);           \
        f[4] = f2bf(wr4[nt * 2 + 1].x); f[5] = f2bf(wr4[nt * 2 + 1].y);       \
        f[6] = f2bf(wr4[nt * 2 + 1].z); f[7] = f2bf(wr4[nt * 2 + 1].w);       \
        wfrag[nt] = f;                                                        \
    }

    // ---- prologue: issue chunks 0,1; zero pad rows; stage chunk 0 ----
    float4 xr0[3], xr1[3], wr0[4], wr1[4];
    ISSUE_X(xr0, 0); ISSUE_W(wr0, 0);
    ISSUE_X(xr1, 1); ISSUE_W(wr1, 1);

    // zero rows 66..79 of both chunk buffers (whole rows: swizzle-invariant)
    for (int i = tid; i < 112; i += NTHREADS) {     // 2 buf x 14 rows x 4 slots
        const int b = i / 56;
        const int r = 66 + (i % 56) / 4;
        *reinterpret_cast<f32x4*>(xlds + b * CBYTES + r * CSTRIDE_B + (i % 4) * 16) =
            (f32x4){0.f, 0.f, 0.f, 0.f};
    }

    WRITE_X(xr0, 0);
    LDS_BARRIER();

    // ---- main loop: 10 chunks, depth-2 register pipeline ----
    f32x4 acc[5][2];
#pragma unroll
    for (int st = 0; st < 5; ++st) {
        acc[st][0] = (f32x4){0.f, 0.f, 0.f, 0.f};
        acc[st][1] = (f32x4){0.f, 0.f, 0.f, 0.f};
    }

    bf16x8 wfrag[2];
#pragma unroll
    for (int c = 0; c < NCHUNK; ++c) {
        // convert W(c) (waits its loads; issued 2 chunks ago)
        if ((c & 1) == 0) { CVT_W(wfrag, wr0); } else { CVT_W(wfrag, wr1); }

        // issue chunk c+2 into the now-free register set
        if (c + 2 < NCHUNK) {
            if ((c & 1) == 0) { ISSUE_X(xr0, c + 2); ISSUE_W(wr0, c + 2); }
            else              { ISSUE_X(xr1, c + 2); ISSUE_W(wr1, c + 2); }
        }

        // MFMA on buffer c&1 : 5 s-tiles x 2 n-tiles
        {
            const int cb = (c & 1) * CBYTES;
#pragma unroll
            for (int st = 0; st < 5; ++st) {
                const int row = st * 16 + lr;
                const int byte = cb + row * CSTRIDE_B + ((lg ^ (row & 3)) << 4);
                const bf16x8 a = *reinterpret_cast<const bf16x8*>(xlds + byte);
                acc[st][0] = __builtin_amdgcn_mfma_f32_16x16x32_bf16(
                    wfrag[0], a, acc[st][0], 0, 0, 0);
                acc[st][1] = __builtin_amdgcn_mfma_f32_16x16x32_bf16(
                    wfrag[1], a, acc[st][1], 0, 0, 0);
            }
        }

        // stage x(c+1) into buffer (c+1)&1 (waits its loads only), then barrier
        if (c + 1 < NCHUNK) {
            if (((c + 1) & 1) == 0) { WRITE_X(xr0, 0); }
            else                    { WRITE_X(xr1, 1); }
            LDS_BARRIER();
        }
    }

    // ---- write t (bf16, swizzled, 8B-packed per n-tile) ----
    // D: col(lane&15)=s-in-tile, row(lg*4+r)=t-col-in-tile
#pragma unroll
    for (int st = 0; st < 5; ++st) {
        const int s = st * 16 + lr;
#pragma unroll
        for (int nt = 0; nt < 2; ++nt) {
            const int c0 = (wv * 2 + nt) * 16 + lg * 4;
            const int byte = (s * TSTRIDE_B + c0 * 2) ^ ((s & 7) << 4);
            s16x4 sv;
            sv[0] = f2bf(acc[st][nt][0]); sv[1] = f2bf(acc[st][nt][1]);
            sv[2] = f2bf(acc[st][nt][2]); sv[3] = f2bf(acc[st][nt][3]);
            *reinterpret_cast<s16x4*>(t_lds + byte) = sv;
        }
    }
    LDS_BARRIER();

    // ---- phase 2: 15 upper-triangle G tiles over 4 waves (slots wv+4*si) ----
    f32x4 g[4];
    int ti[4], tj[4];
    bool valid[4], isdiag[4];
#pragma unroll
    for (int si = 0; si < 4; ++si) {
        const int pos = wv + si * 4;
        valid[si] = pos < 15;
        g[si] = (f32x4){0.f, 0.f, 0.f, 0.f};
        ti[si] = 0; tj[si] = 0; isdiag[si] = false;
        if (valid[si]) {
            ti[si] = TI_LUT[pos]; tj[si] = TJ_LUT[pos];
            isdiag[si] = pos < 5;
#pragma unroll
            for (int kk = 0; kk < 4; ++kk) {
                const int ra = ti[si] * 16 + lr;
                const int ba = (ra * TSTRIDE_B + kk * 64 + lg * 16) ^ ((ra & 7) << 4);
                const int rb = tj[si] * 16 + lr;
                const int bb = (rb * TSTRIDE_B + kk * 64 + lg * 16) ^ ((rb & 7) << 4);
                g[si] = __builtin_amdgcn_mfma_f32_16x16x32_bf16(
                    *reinterpret_cast<const bf16x8*>(t_lds + ba),
                    *reinterpret_cast<const bf16x8*>(t_lds + bb), g[si], 0, 0, 0);
            }
            if (isdiag[si]) {                   // diagonal: extract norms
#pragma unroll
                for (int r = 0; r < 4; ++r)
                    if (lr == lg * 4 + r) norms[ti[si] * 16 + lr] = g[si][r];
            }
        }
    }
    LDS_BARRIER();

    // ---- epilogue: out[i][j] = norms[i] + norms[j] - 2 G[i][j] (+mirror) ----
    float* __restrict__ ob = out + (size_t)batch * NS * NS;
#pragma unroll
    for (int si = 0; si < 4; ++si) {
        if (valid[si]) {
            const int j = tj[si] * 16 + lr;
            const float nj = norms[j];
            float v[4];
#pragma unroll
            for (int r = 0; r < 4; ++r) {
                const int i_ = ti[si] * 16 + lg * 4 + r;
                v[r] = norms[i_] + nj - 2.f * g[si][r];
                if (i_ < NS && j < NS) ob[i_ * NS + j] = v[r];
            }
            if (!isdiag[si] && j < NS) {        // strict-upper: vectorized mirror
                const int i0 = ti[si] * 16 + lg * 4;   // ti<=3 -> i0+3 <= 63 < NS
                *reinterpret_cast<float2*>(ob + j * NS + i0)     = make_float2(v[0], v[1]);
                *reinterpret_cast<float2*>(ob + j * NS + i0 + 2) = make_float2(v[2], v[3]);
            }
        }
    }
#undef ISSUE_X
#undef ISSUE_W
#undef WRITE_X
#undef CVT_W
}

extern "C" void kernel_launch(void* const* d_in, const int* in_sizes, int n_in,
                              void* d_out, int out_size, void* d_ws, size_t ws_size,
                              hipStream_t stream) {
    const float* x = (const float*)d_in[0];   // (512, 66, 304) f32
    const float* W = (const float*)d_in[1];   // (128, 304) f32
    // d_in[2] = b : cancels in the pairwise difference, unused.
    float* out = (float*)d_out;               // (512, 66, 66) f32

    treeprobe_mfma<<<NBATCH, NTHREADS, 0, stream>>>(x, W, out);
}

// Round 11
// 20.999 us; speedup vs baseline: 1.1610x; 1.1610x over previous
//
#include <hip/hip_runtime.h>
#include <hip/hip_bf16.h>

#define NBATCH 512
#define NS 66
#define ND 304
#define NK 128
#define NTHREADS 640            // 10 waves: (M-tile 0..4) x (N-half 0..1)
#define NBLOCKS (NBATCH / 2)    // persistent: 2 batches per block

#define WSTRIDE_B 640                       // 320 bf16 per W row (k padded)
#define WLDS_BYTES (128 * WSTRIDE_B)        // 81920
#define TSTRIDE_B 256                       // 128 bf16 per t row
#define TBYTES (80 * TSTRIDE_B)             // 20480

typedef __attribute__((ext_vector_type(8))) short bf16x8;
typedef __attribute__((ext_vector_type(4))) short s16x4;
typedef __attribute__((ext_vector_type(4))) float f32x4;

__device__ __forceinline__ short f2bf(float x) {
    return __builtin_bit_cast(short, __float2bfloat16(x));
}

// 15 upper-triangle 16x16 tiles of G: 5 diagonal first, then 10 strict-upper.
__device__ const int TI_LUT[15] = {0,1,2,3,4, 0,0,0,0,1,1,1,2,2,3};
__device__ const int TJ_LUT[15] = {0,1,2,3,4, 1,2,3,4,2,3,4,3,4,4};

// raw barrier: waits this wave's LDS ops + all waves arrive; vmem stays in flight
#define LDS_BARRIER() asm volatile("s_waitcnt lgkmcnt(0)\n\ts_barrier" ::: "memory")

__global__ __launch_bounds__(NTHREADS, 2) void treeprobe_mfma(
    const float* __restrict__ x,   // [512][66][304]
    const float* __restrict__ W,   // [128][304]
    float* __restrict__ out)       // [512][66][66]
{
    __shared__ __align__(16) char w_lds[WLDS_BYTES];   // W bf16, swizzled
    __shared__ __align__(16) char t_lds[TBYTES];       // t bf16, swizzled
    __shared__ float norms[80];

    const int tid  = threadIdx.x;
    const int lane = tid & 63;
    const int wv   = tid >> 6;      // 0..9
    const int mt   = wv >> 1;       // M-tile 0..4 (16 s-rows)
    const int nh   = wv & 1;        // N-half (64 t-cols)
    const int lr   = lane & 15;
    const int lg   = lane >> 4;     // 0..3

    const int b0 = blockIdx.x * 2;
    const int xrow = mt * 16 + lr;                 // s row 0..79
    const bool rowok = xrow < NS;
    const float* __restrict__ xr0p = x + ((size_t)b0 * NS + xrow) * ND;
    const float* __restrict__ xr1p = xr0p + NS * ND;

    // issue x quad-pair for k-chunk kk of this lane's row into float4 d[2]
#define XQ(d, rp, kk) do {                                                    \
        const int k0_ = (kk) * 32 + lg * 8;                                   \
        if (rowok && k0_ < ND) {                                              \
            d[0] = *reinterpret_cast<const float4*>((rp) + k0_);              \
            d[1] = *reinterpret_cast<const float4*>((rp) + k0_ + 4);          \
        } else {                                                              \
            d[0] = make_float4(0.f, 0.f, 0.f, 0.f);                           \
            d[1] = make_float4(0.f, 0.f, 0.f, 0.f);                           \
        }                                                                     \
    } while (0)

    // ---- issue x(b0) chunks 0,1 first (stream under W staging) ----
    float4 xqa[2], xqb[2];
    XQ(xqa, xr0p, 0);
    XQ(xqb, xr0p, 1);

    // ---- stage W -> bf16 LDS, swizzled, ONCE (9728 float4, 8 in flight) ----
    {
        float4 wbuf[8];
#pragma unroll
        for (int o = 0; o < 2; ++o) {
#pragma unroll
            for (int j = 0; j < 8; ++j) {
                const int e = tid + (o * 8 + j) * NTHREADS;
                wbuf[j] = (e < 9728)
                    ? *reinterpret_cast<const float4*>(W + (e / 76) * ND + (e % 76) * 4)
                    : make_float4(0.f, 0.f, 0.f, 0.f);
            }
#pragma unroll
            for (int j = 0; j < 8; ++j) {
                const int e = tid + (o * 8 + j) * NTHREADS;
                if (e < 9728) {
                    const int row = e / 76, q = e % 76;
                    const int byte =
                        ((row * WSTRIDE_B + (q >> 1) * 16) ^ ((row & 7) << 4)) | ((q & 1) << 3);
                    s16x4 sv;
                    sv[0] = f2bf(wbuf[j].x); sv[1] = f2bf(wbuf[j].y);
                    sv[2] = f2bf(wbuf[j].z); sv[3] = f2bf(wbuf[j].w);
                    *reinterpret_cast<s16x4*>(w_lds + byte) = sv;
                }
            }
        }
        // zero k-pad slots 38,39 (k 304..319) for all 128 rows
        for (int i = tid; i < 256; i += NTHREADS) {
            const int row = i >> 1;
            const int byte = (row * WSTRIDE_B + (38 + (i & 1)) * 16) ^ ((row & 7) << 4);
            *reinterpret_cast<f32x4*>(w_lds + byte) = (f32x4){0.f, 0.f, 0.f, 0.f};
        }
    }
    LDS_BARRIER();      // W visible; x chunk 0,1 loads still in flight

#define CVT_B(bf, d) do {                                                     \
        bf[0] = f2bf(d[0].x); bf[1] = f2bf(d[0].y);                           \
        bf[2] = f2bf(d[0].z); bf[3] = f2bf(d[0].w);                           \
        bf[4] = f2bf(d[1].x); bf[5] = f2bf(d[1].y);                           \
        bf[6] = f2bf(d[1].z); bf[7] = f2bf(d[1].w);                           \
    } while (0)

    // one phase-1 k-step: cvt CUR, reissue CUR for kk+2, 4x (W ds_read + MFMA)
#define PH1_STEP(kk, CUR, rp) do {                                            \
        bf16x8 bfr;                                                           \
        CVT_B(bfr, CUR);                                                      \
        if ((kk) + 2 < 10) { XQ(CUR, rp, (kk) + 2); }                         \
        _Pragma("unroll")                                                     \
        for (int nt = 0; nt < 4; ++nt) {                                      \
            const int wrow = nh * 64 + nt * 16 + lr;                          \
            const int byte =                                                  \
                (wrow * WSTRIDE_B + (kk) * 64 + lg * 16) ^ ((wrow & 7) << 4); \
            const bf16x8 wfr = *reinterpret_cast<const bf16x8*>(w_lds + byte);\
            acc[nt] = __builtin_amdgcn_mfma_f32_16x16x32_bf16(                \
                wfr, bfr, acc[nt], 0, 0, 0);                                  \
        }                                                                     \
    } while (0)

#define RUN_BATCH(rp, obptr, DO_PREFETCH, rpn) do {                           \
        f32x4 acc[4];                                                         \
        acc[0] = (f32x4){0.f,0.f,0.f,0.f}; acc[1] = (f32x4){0.f,0.f,0.f,0.f}; \
        acc[2] = (f32x4){0.f,0.f,0.f,0.f}; acc[3] = (f32x4){0.f,0.f,0.f,0.f}; \
        /* phase 1: barrier-free; x streams into regs, W from LDS */          \
        PH1_STEP(0, xqa, rp); PH1_STEP(1, xqb, rp);                           \
        PH1_STEP(2, xqa, rp); PH1_STEP(3, xqb, rp);                           \
        PH1_STEP(4, xqa, rp); PH1_STEP(5, xqb, rp);                           \
        PH1_STEP(6, xqa, rp); PH1_STEP(7, xqb, rp);                           \
        PH1_STEP(8, xqa, rp); PH1_STEP(9, xqb, rp);                           \
        /* write t: D col(lr)=s(==xrow), row(lg*4+r)=c -> 8B packed */        \
        _Pragma("unroll")                                                     \
        for (int nt = 0; nt < 4; ++nt) {                                      \
            const int c0 = nh * 64 + nt * 16 + lg * 4;                        \
            const int byte = (xrow * TSTRIDE_B + c0 * 2) ^ ((xrow & 7) << 4); \
            s16x4 sv;                                                         \
            sv[0] = f2bf(acc[nt][0]); sv[1] = f2bf(acc[nt][1]);               \
            sv[2] = f2bf(acc[nt][2]); sv[3] = f2bf(acc[nt][3]);               \
            *reinterpret_cast<s16x4*>(t_lds + byte) = sv;                     \
        }                                                                     \
        LDS_BARRIER();                                                        \
        if (DO_PREFETCH) { XQ(xqa, rpn, 0); XQ(xqb, rpn, 1); }                \
        /* phase 2: 15 G tiles over 10 waves (pos = wv, wv+10) */             \
        f32x4 g[2]; int ti[2], tj[2]; bool val[2], dia[2];                    \
        _Pragma("unroll")                                                     \
        for (int si = 0; si < 2; ++si) {                                      \
            const int pos = wv + si * 10;                                     \
            val[si] = pos < 15;                                               \
            g[si] = (f32x4){0.f,0.f,0.f,0.f};                                 \
            ti[si] = 0; tj[si] = 0; dia[si] = false;                          \
            if (val[si]) {                                                    \
                ti[si] = TI_LUT[pos]; tj[si] = TJ_LUT[pos];                   \
                dia[si] = pos < 5;                                            \
                _Pragma("unroll")                                             \
                for (int kk = 0; kk < 4; ++kk) {                              \
                    const int ra = ti[si] * 16 + lr;                          \
                    const int ba =                                            \
                        (ra * TSTRIDE_B + kk * 64 + lg * 16) ^ ((ra & 7) << 4);\
                    const int rb = tj[si] * 16 + lr;                          \
                    const int bb =                                            \
                        (rb * TSTRIDE_B + kk * 64 + lg * 16) ^ ((rb & 7) << 4);\
                    g[si] = __builtin_amdgcn_mfma_f32_16x16x32_bf16(          \
                        *reinterpret_cast<const bf16x8*>(t_lds + ba),         \
                        *reinterpret_cast<const bf16x8*>(t_lds + bb),         \
                        g[si], 0, 0, 0);                                      \
                }                                                             \
                if (dia[si]) {                                                \
                    _Pragma("unroll")                                         \
                    for (int r = 0; r < 4; ++r)                               \
                        if (lr == lg * 4 + r) norms[ti[si] * 16 + lr] = g[si][r];\
                }                                                             \
            }                                                                 \
        }                                                                     \
        LDS_BARRIER();                                                        \
        /* epilogue: out = norms_i + norms_j - 2G (+mirror for strict-upper) */\
        _Pragma("unroll")                                                     \
        for (int si = 0; si < 2; ++si) {                                      \
            if (val[si]) {                                                    \
                const int j = tj[si] * 16 + lr;                               \
                const float nj = norms[j];                                    \
                float v[4];                                                   \
                _Pragma("unroll")                                             \
                for (int r = 0; r < 4; ++r) {                                 \
                    const int i_ = ti[si] * 16 + lg * 4 + r;                  \
                    v[r] = norms[i_] + nj - 2.f * g[si][r];                   \
                    if (i_ < NS && j < NS) (obptr)[i_ * NS + j] = v[r];       \
                }                                                             \
                if (!dia[si] && j < NS) {                                     \
                    const int i0 = ti[si] * 16 + lg * 4;  /* ti<=3 -> <64 */  \
                    *reinterpret_cast<float2*>((obptr) + j * NS + i0) =       \
                        make_float2(v[0], v[1]);                              \
                    *reinterpret_cast<float2*>((obptr) + j * NS + i0 + 2) =   \
                        make_float2(v[2], v[3]);                              \
                }                                                             \
            }                                                                 \
        }                                                                     \
    } while (0)

    float* __restrict__ ob0 = out + (size_t)b0 * NS * NS;
    float* __restrict__ ob1 = ob0 + NS * NS;

    RUN_BATCH(xr0p, ob0, 1, xr1p);   // batch b0, prefetch b1 during phase 2
    RUN_BATCH(xr1p, ob1, 0, xr1p);   // batch b1

#undef XQ
#undef CVT_B
#undef PH1_STEP
#undef RUN_BATCH
}

extern "C" void kernel_launch(void* const* d_in, const int* in_sizes, int n_in,
                              void* d_out, int out_size, void* d_ws, size_t ws_size,
                              hipStream_t stream) {
    const float* x = (const float*)d_in[0];   // (512, 66, 304) f32
    const float* W = (const float*)d_in[1];   // (128, 304) f32
    // d_in[2] = b : cancels in the pairwise difference, unused.
    float* out = (float*)d_out;               // (512, 66, 66) f32

    treeprobe_mfma<<<NBLOCKS, NTHREADS, 0, stream>>>(x, W, out);
}